// Round 4
// baseline (349.687 us; speedup 1.0000x reference)
//
#include <hip/hip_runtime.h>
#include <math.h>

// Problem dims
#define BT 64       // B*N sequences
#define T 256
#define DM 128      // d_model
#define DI 256      // d_inner
#define DS 16       // d_state
#define DR 8        // dt_rank
#define M_ROWS (BT*T)   // 16384
#define NC 16       // time chunks for parallel scan
#define CL (T/NC)   // chunk length = 16
#define SSZ (BT*DI*DS)  // per-chunk state slab = 262144

__device__ __forceinline__ float fast_silu(float x) {
  return x * __builtin_amdgcn_rcpf(1.0f + __expf(-x));
}
__device__ __forceinline__ float softplus_f(float x) {
  return fmaxf(x, 0.0f) + __logf(1.0f + __expf(-fabsf(x)));
}
// P is stored in the dead u-pre half of xz (cols 0..255 of each 512-wide row)
__device__ __forceinline__ size_t paddr(size_t f) {
  return (f >> 8) * 512 + (f & 255);
}

// ---------------- 128x64-tile fp32 GEMM: C[M,N] = A[M,K] @ W[K,N] ----------------
// EPI=0: plain store to C (row stride N)
// EPI=1: deltaBC epilogue: cols<256 -> softplus(acc+dtb[col]) -> C (delta, stride DI);
//        cols 256..271 -> Bb, 272..287 -> Cb, >=288 discard (W zero-padded)
template <int EPI>
__global__ __launch_bounds__(256) void gemm128(
    const float* __restrict__ A, const float* __restrict__ W,
    float* __restrict__ C, float* __restrict__ Bb, float* __restrict__ Cb,
    const float* __restrict__ dtb, int M, int N, int K) {
  __shared__ float sA[32][132];   // [k][row], stride 132 keeps float4 align, ~4-way write conflict
  __shared__ float sB[32][64];    // [k][col]
  const int bm0 = blockIdx.x * 128;
  const int bn0 = blockIdx.y * 64;
  const int tid = threadIdx.x;
  const int tx = tid & 15;        // 16 col-groups of 4
  const int ty = tid >> 4;        // 16 row-groups of 8

  float acc[8][4] = {};

  for (int k0 = 0; k0 < K; k0 += 32) {
#pragma unroll
    for (int i = 0; i < 4; i++) {
      int f = tid + i * 256;           // 0..1023 float4-slots of A tile
      int r = f >> 3;                  // 0..127
      int c4 = f & 7;                  // 0..7
      const float4 v = *reinterpret_cast<const float4*>(
          &A[(size_t)(bm0 + r) * K + k0 + c4 * 4]);
      sA[c4 * 4 + 0][r] = v.x;
      sA[c4 * 4 + 1][r] = v.y;
      sA[c4 * 4 + 2][r] = v.z;
      sA[c4 * 4 + 3][r] = v.w;
    }
#pragma unroll
    for (int i = 0; i < 2; i++) {
      int f = tid + i * 256;           // 0..511
      int kr = f >> 4;                 // 0..31
      int c4 = f & 15;                 // 0..15
      *reinterpret_cast<float4*>(&sB[kr][c4 * 4]) =
          *reinterpret_cast<const float4*>(&W[(size_t)(k0 + kr) * N + bn0 + c4 * 4]);
    }
    __syncthreads();

#pragma unroll
    for (int k = 0; k < 32; k++) {
      const float4 a0 = *reinterpret_cast<const float4*>(&sA[k][ty * 8]);
      const float4 a1 = *reinterpret_cast<const float4*>(&sA[k][ty * 8 + 4]);
      const float4 bv = *reinterpret_cast<const float4*>(&sB[k][tx * 4]);
      float a[8] = {a0.x, a0.y, a0.z, a0.w, a1.x, a1.y, a1.z, a1.w};
      float b[4] = {bv.x, bv.y, bv.z, bv.w};
#pragma unroll
      for (int i = 0; i < 8; i++)
#pragma unroll
        for (int j = 0; j < 4; j++)
          acc[i][j] += a[i] * b[j];
    }
    __syncthreads();
  }

  if (EPI == 0) {
#pragma unroll
    for (int i = 0; i < 8; i++) {
      float4 v = {acc[i][0], acc[i][1], acc[i][2], acc[i][3]};
      *reinterpret_cast<float4*>(&C[(size_t)(bm0 + ty * 8 + i) * N + bn0 + tx * 4]) = v;
    }
  } else {
    if (bn0 < 256) {
      const int col = bn0 + tx * 4;
      const float4 bias = *reinterpret_cast<const float4*>(&dtb[col]);
#pragma unroll
      for (int i = 0; i < 8; i++) {
        const size_t m = bm0 + ty * 8 + i;
        float4 v;
        v.x = softplus_f(acc[i][0] + bias.x);
        v.y = softplus_f(acc[i][1] + bias.y);
        v.z = softplus_f(acc[i][2] + bias.z);
        v.w = softplus_f(acc[i][3] + bias.w);
        *reinterpret_cast<float4*>(&C[m * DI + col]) = v;
      }
    } else {
      const int col = tx * 4;    // 0..63 within the BC tile
      if (col < 16) {
#pragma unroll
        for (int i = 0; i < 8; i++) {
          const size_t m = bm0 + ty * 8 + i;
          float4 v = {acc[i][0], acc[i][1], acc[i][2], acc[i][3]};
          *reinterpret_cast<float4*>(&Bb[m * DS + col]) = v;
        }
      } else if (col < 32) {
#pragma unroll
        for (int i = 0; i < 8; i++) {
          const size_t m = bm0 + ty * 8 + i;
          float4 v = {acc[i][0], acc[i][1], acc[i][2], acc[i][3]};
          *reinterpret_cast<float4*>(&Cb[m * DS + (col - 16)]) = v;
        }
      }
    }
  }
}

// ---------------- W_big precompute: [l][256 k][320] = [xw_dt @ dtw | xw_BC | 0pad] ----------------
__global__ __launch_bounds__(320) void build_wbig(
    const float* __restrict__ xw, const float* __restrict__ dtw,
    float* __restrict__ Wbig) {
  const int k = blockIdx.x;      // 0..255
  const int l = blockIdx.y;      // 0..1
  const int j = threadIdx.x;     // 0..319
  float v = 0.f;
  if (j < 256) {
#pragma unroll
    for (int r = 0; r < DR; r++)
      v += xw[(size_t)l * DI * 40 + k * 40 + r] * dtw[(size_t)l * DR * DI + r * DI + j];
  } else if (j < 288) {
    v = xw[(size_t)l * DI * 40 + k * 40 + 8 + (j - 256)];
  }
  Wbig[(size_t)l * DI * 320 + k * 320 + j] = v;
}

// ---------------- depthwise causal conv (4-tap) + bias + silu; also silu(res) in place ----------------
__global__ __launch_bounds__(256) void conv_silu_kernel(
    const float* __restrict__ xzr, float* __restrict__ xzw,
    const float* __restrict__ cw, const float* __restrict__ cb,
    float* __restrict__ u) {
  const int m = blockIdx.x;          // (bt*T + t)
  const int d = threadIdx.x;         // 0..255
  const int t = m & (T - 1);
  float acc = cb[d];
#pragma unroll
  for (int j = 0; j < 4; j++) {
    int tt = t - 3 + j;
    if (tt >= 0)
      acc += xzr[(size_t)(m - 3 + j) * 512 + d] * cw[d * 4 + j];
  }
  u[(size_t)m * DI + d] = fast_silu(acc);
  const size_t ra = (size_t)m * 512 + 256 + d;
  xzw[ra] = fast_silu(xzr[ra]);
}

// ---------------- chunked parallel scan (all 16 n-states per thread) ----------------
__global__ __launch_bounds__(256) void scan_phase1(
    const float* __restrict__ delta, const float* __restrict__ u,
    const float* __restrict__ Bb, const float* __restrict__ A_log,
    float* __restrict__ Pal, float* __restrict__ H) {
  const int c  = blockIdx.x;
  const int bt = blockIdx.y;
  const int d  = threadIdx.x;

  float An[16];
  const float4* al = reinterpret_cast<const float4*>(&A_log[d * DS]);
#pragma unroll
  for (int q = 0; q < 4; q++) {
    float4 a = al[q];
    An[q * 4 + 0] = -__expf(a.x);
    An[q * 4 + 1] = -__expf(a.y);
    An[q * 4 + 2] = -__expf(a.z);
    An[q * 4 + 3] = -__expf(a.w);
  }

  float h[16];
#pragma unroll
  for (int n = 0; n < 16; n++) h[n] = 0.f;
  float Sdl = 0.f;

  const size_t m0 = (size_t)bt * T + c * CL;
  for (int t = 0; t < CL; t++) {
    const size_t m = m0 + t;
    const float dl = delta[m * DI + d];
    const float uu = u[m * DI + d];
    const float du = dl * uu;
    Sdl += dl;
    const float4* bp = reinterpret_cast<const float4*>(&Bb[m * DS]);
    const float4 B0 = bp[0], B1 = bp[1], B2 = bp[2], B3 = bp[3];
    const float Bv[16] = {B0.x, B0.y, B0.z, B0.w, B1.x, B1.y, B1.z, B1.w,
                          B2.x, B2.y, B2.z, B2.w, B3.x, B3.y, B3.z, B3.w};
#pragma unroll
    for (int n = 0; n < 16; n++) {
      const float dA = __expf(dl * An[n]);
      h[n] = dA * h[n] + du * Bv[n];
    }
  }

  const size_t idx = ((size_t)c * BT + bt) * 4096 + (size_t)d * 16;
#pragma unroll
  for (int q = 0; q < 4; q++) {
    float4 hv = {h[q * 4 + 0], h[q * 4 + 1], h[q * 4 + 2], h[q * 4 + 3]};
    *reinterpret_cast<float4*>(&H[idx + q * 4]) = hv;
  }
#pragma unroll
  for (int q = 0; q < 4; q++) {
    float4 pv = {__expf(An[q * 4 + 0] * Sdl), __expf(An[q * 4 + 1] * Sdl),
                 __expf(An[q * 4 + 2] * Sdl), __expf(An[q * 4 + 3] * Sdl)};
    *reinterpret_cast<float4*>(&Pal[paddr(idx + q * 4)]) = pv;
  }
}

__global__ __launch_bounds__(256) void scan_phase2(
    const float* __restrict__ Pal, float* __restrict__ H) {
  const size_t i = (size_t)blockIdx.x * 256 + threadIdx.x;   // 0..SSZ-1
  float hin = 0.f;
#pragma unroll
  for (int c = 0; c < NC; c++) {
    const size_t idx = (size_t)c * SSZ + i;
    const float Pv = Pal[paddr(idx)];
    const float Hv = H[idx];
    H[idx] = hin;
    hin = Pv * hin + Hv;
  }
}

__global__ __launch_bounds__(256) void scan_phase3(
    const float* __restrict__ delta, const float* __restrict__ u,
    const float* __restrict__ Bb, const float* __restrict__ Cb,
    const float* __restrict__ xz,            // res half pre-silu'd by conv kernel
    const float* __restrict__ A_log, const float* __restrict__ Dp,
    const float* __restrict__ H, float* __restrict__ g) {
  const int c  = blockIdx.x;
  const int bt = blockIdx.y;
  const int d  = threadIdx.x;

  float An[16];
  const float4* al = reinterpret_cast<const float4*>(&A_log[d * DS]);
#pragma unroll
  for (int q = 0; q < 4; q++) {
    float4 a = al[q];
    An[q * 4 + 0] = -__expf(a.x);
    An[q * 4 + 1] = -__expf(a.y);
    An[q * 4 + 2] = -__expf(a.z);
    An[q * 4 + 3] = -__expf(a.w);
  }
  const float Dpd = Dp[d];

  float h[16];
  const size_t idx = ((size_t)c * BT + bt) * 4096 + (size_t)d * 16;
#pragma unroll
  for (int q = 0; q < 4; q++) {
    float4 hv = *reinterpret_cast<const float4*>(&H[idx + q * 4]);
    h[q * 4 + 0] = hv.x; h[q * 4 + 1] = hv.y; h[q * 4 + 2] = hv.z; h[q * 4 + 3] = hv.w;
  }

  const size_t m0 = (size_t)bt * T + c * CL;
  for (int t = 0; t < CL; t++) {
    const size_t m = m0 + t;
    const float dl = delta[m * DI + d];
    const float uu = u[m * DI + d];
    const float du = dl * uu;
    const float4* bp = reinterpret_cast<const float4*>(&Bb[m * DS]);
    const float4 B0 = bp[0], B1 = bp[1], B2 = bp[2], B3 = bp[3];
    const float4* cp = reinterpret_cast<const float4*>(&Cb[m * DS]);
    const float4 C0 = cp[0], C1 = cp[1], C2 = cp[2], C3 = cp[3];
    const float Bv[16] = {B0.x, B0.y, B0.z, B0.w, B1.x, B1.y, B1.z, B1.w,
                          B2.x, B2.y, B2.z, B2.w, B3.x, B3.y, B3.z, B3.w};
    const float Cv[16] = {C0.x, C0.y, C0.z, C0.w, C1.x, C1.y, C1.z, C1.w,
                          C2.x, C2.y, C2.z, C2.w, C3.x, C3.y, C3.z, C3.w};
    float y = 0.f;
#pragma unroll
    for (int n = 0; n < 16; n++) {
      const float dA = __expf(dl * An[n]);
      h[n] = dA * h[n] + du * Bv[n];
      y += h[n] * Cv[n];
    }
    const float rs = xz[m * 512 + 256 + d];       // already silu'd
    g[m * DI + d] = (y + uu * Dpd) * rs;          // aliases delta (same-thread RAW only)
  }
}

// ---------------- launch ----------------
extern "C" void kernel_launch(void* const* d_in, const int* in_sizes, int n_in,
                              void* d_out, int out_size, void* d_ws, size_t ws_size,
                              hipStream_t stream) {
  const float* x      = (const float*)d_in[0];
  const float* in_w   = (const float*)d_in[1];   // [2,128,512]
  const float* conv_w = (const float*)d_in[2];   // [2,256,1,4]
  const float* conv_b = (const float*)d_in[3];   // [2,256]
  const float* xw     = (const float*)d_in[4];   // [2,256,40]
  const float* dtw    = (const float*)d_in[5];   // [2,8,256]
  const float* dtb    = (const float*)d_in[6];   // [2,256]
  const float* A_log  = (const float*)d_in[7];   // [2,256,16]
  const float* Dp     = (const float*)d_in[8];   // [2,256]
  const float* ow     = (const float*)d_in[9];   // [2,256,128]
  float* out = (float*)d_out;
  float* ws  = (float*)d_ws;

  float* xz = ws;                          // 16384*512; u-pre half hosts P after conv
  float* u  = ws + 8388608;                // 16384*256
  float* dg = ws + 12582912;               // 16384*256 (delta, then g alias)
  float* Bb = ws + 16777216;               // 16384*16
  float* Cb = ws + 17039360;               // 16384*16
  float* hb = ws + 17301504;               // 16384*128
  float* Hb = ws + 19398656;               // NC*SSZ = 4194304 (end 23592960 floats = 94.4MB)
  // W_big scratch lives in d_out (only the final GEMM writes d_out, after last read of W_big)
  float* Wbig = out;                       // 2*256*320 = 163840 <= out_size (2097152)

  build_wbig<<<dim3(DI, 2), 320, 0, stream>>>(xw, dtw, Wbig);

  for (int l = 0; l < 2; l++) {
    const float* Ain = (l == 0) ? x : hb;
    float* dst = (l == 1) ? out : hb;

    gemm128<0><<<dim3(M_ROWS / 128, 512 / 64), 256, 0, stream>>>(
        Ain, in_w + (size_t)l * DM * 2 * DI, xz, nullptr, nullptr, nullptr,
        M_ROWS, 2 * DI, DM);

    conv_silu_kernel<<<M_ROWS, 256, 0, stream>>>(
        xz, xz, conv_w + (size_t)l * DI * 4, conv_b + (size_t)l * DI, u);

    gemm128<1><<<dim3(M_ROWS / 128, 320 / 64), 256, 0, stream>>>(
        u, Wbig + (size_t)l * DI * 320, dg, Bb, Cb, dtb + (size_t)l * DI,
        M_ROWS, 320, DI);

    scan_phase1<<<dim3(NC, BT), 256, 0, stream>>>(
        dg, u, Bb, A_log + (size_t)l * DI * DS, xz, Hb);

    scan_phase2<<<SSZ / 256, 256, 0, stream>>>(xz, Hb);

    scan_phase3<<<dim3(NC, BT), 256, 0, stream>>>(
        dg, u, Bb, Cb, xz, A_log + (size_t)l * DI * DS, Dp + (size_t)l * DI,
        Hb, dg);

    gemm128<0><<<dim3(M_ROWS / 128, DM / 64), 256, 0, stream>>>(
        dg, ow + (size_t)l * DI * DM, dst, nullptr, nullptr, nullptr,
        M_ROWS, DM, DI);
  }
}

// Round 5
// 335.976 us; speedup vs baseline: 1.0408x; 1.0408x over previous
//
#include <hip/hip_runtime.h>
#include <math.h>

// Problem dims
#define BT 64       // B*N sequences
#define T 256
#define DM 128      // d_model
#define DI 256      // d_inner
#define DS 16       // d_state
#define DR 8        // dt_rank
#define M_ROWS (BT*T)   // 16384
#define NC 16       // time chunks for parallel scan
#define CL (T/NC)   // chunk length = 16
#define SSZ (BT*DI*DS)  // per-chunk state slab = 262144

__device__ __forceinline__ float fast_silu(float x) {
  return x * __builtin_amdgcn_rcpf(1.0f + __expf(-x));
}
__device__ __forceinline__ float softplus_f(float x) {
  return fmaxf(x, 0.0f) + __logf(1.0f + __expf(-fabsf(x)));
}
// P is stored in the dead u-pre half of xz (cols 0..255 of each 512-wide row)
__device__ __forceinline__ size_t paddr(size_t f) {
  return (f >> 8) * 512 + (f & 255);
}

// ---------------- 64x64-tile fp32 GEMM, register-prefetch double buffer ----------------
// sA stride 66: transposed-store banks (8*c4+2q+r)%32 -> exactly 2 lanes/bank (free);
// reads as 2x ds_read_b64 (8B aligned).
// EPI=0: plain store. EPI=1: cols<256 softplus(+dtb)->delta; 256..271->Bb; 272..287->Cb.
#define SAS 66
template <int EPI>
__global__ __launch_bounds__(256) void gemm64(
    const float* __restrict__ A, const float* __restrict__ W,
    float* __restrict__ C, float* __restrict__ Bb, float* __restrict__ Cb,
    const float* __restrict__ dtb, int M, int N, int K) {
  __shared__ float sA[32][SAS];   // [k][row]
  __shared__ float sB[32][64];    // [k][col]
  const int bm0 = blockIdx.x * 64;
  const int bn0 = blockIdx.y * 64;
  const int tid = threadIdx.x;
  const int tx = tid & 15;
  const int ty = tid >> 4;

  // A-tile slots: f = tid + i*256, i=0..1 -> r=f>>3 (0..63), c4=f&7
  const int ar0 = tid >> 3, ac4 = tid & 7;
  // B-tile slots: kr=f>>4, c4=f&15
  const int bk0 = tid >> 4, bc4 = tid & 15;

  float4 pa0, pa1, pb0, pb1;
  const int NT = K >> 5;

  // prefetch tile 0
  {
    pa0 = *reinterpret_cast<const float4*>(&A[(size_t)(bm0 + ar0) * K + ac4 * 4]);
    pa1 = *reinterpret_cast<const float4*>(&A[(size_t)(bm0 + ar0 + 32) * K + ac4 * 4]);
    pb0 = *reinterpret_cast<const float4*>(&W[(size_t)(bk0)*N + bn0 + bc4 * 4]);
    pb1 = *reinterpret_cast<const float4*>(&W[(size_t)(bk0 + 16) * N + bn0 + bc4 * 4]);
  }

  float acc[4][4] = {};

  for (int t = 0; t < NT; t++) {
    if (t > 0) __syncthreads();             // previous compute done before overwrite
    // store prefetched tile to LDS (A transposed, scalar; banks 2-way -> free)
    sA[ac4 * 4 + 0][ar0] = pa0.x;
    sA[ac4 * 4 + 1][ar0] = pa0.y;
    sA[ac4 * 4 + 2][ar0] = pa0.z;
    sA[ac4 * 4 + 3][ar0] = pa0.w;
    sA[ac4 * 4 + 0][ar0 + 32] = pa1.x;
    sA[ac4 * 4 + 1][ar0 + 32] = pa1.y;
    sA[ac4 * 4 + 2][ar0 + 32] = pa1.z;
    sA[ac4 * 4 + 3][ar0 + 32] = pa1.w;
    *reinterpret_cast<float4*>(&sB[bk0][bc4 * 4]) = pb0;
    *reinterpret_cast<float4*>(&sB[bk0 + 16][bc4 * 4]) = pb1;
    __syncthreads();

    if (t + 1 < NT) {                       // issue next-tile loads; hide under compute
      const int k0 = (t + 1) << 5;
      pa0 = *reinterpret_cast<const float4*>(&A[(size_t)(bm0 + ar0) * K + k0 + ac4 * 4]);
      pa1 = *reinterpret_cast<const float4*>(&A[(size_t)(bm0 + ar0 + 32) * K + k0 + ac4 * 4]);
      pb0 = *reinterpret_cast<const float4*>(&W[(size_t)(k0 + bk0) * N + bn0 + bc4 * 4]);
      pb1 = *reinterpret_cast<const float4*>(&W[(size_t)(k0 + bk0 + 16) * N + bn0 + bc4 * 4]);
    }

#pragma unroll
    for (int k = 0; k < 32; k++) {
      const float2 a0 = *reinterpret_cast<const float2*>(&sA[k][ty * 4]);
      const float2 a1 = *reinterpret_cast<const float2*>(&sA[k][ty * 4 + 2]);
      const float4 bv = *reinterpret_cast<const float4*>(&sB[k][tx * 4]);
      float a[4] = {a0.x, a0.y, a1.x, a1.y};
      float b[4] = {bv.x, bv.y, bv.z, bv.w};
#pragma unroll
      for (int i = 0; i < 4; i++)
#pragma unroll
        for (int j = 0; j < 4; j++)
          acc[i][j] += a[i] * b[j];
    }
  }

  if (EPI == 0) {
#pragma unroll
    for (int i = 0; i < 4; i++) {
      float4 v = {acc[i][0], acc[i][1], acc[i][2], acc[i][3]};
      *reinterpret_cast<float4*>(&C[(size_t)(bm0 + ty * 4 + i) * N + bn0 + tx * 4]) = v;
    }
  } else {
    if (bn0 < 256) {
      const int col = bn0 + tx * 4;
      const float4 bias = *reinterpret_cast<const float4*>(&dtb[col]);
#pragma unroll
      for (int i = 0; i < 4; i++) {
        const size_t m = bm0 + ty * 4 + i;
        float4 v;
        v.x = softplus_f(acc[i][0] + bias.x);
        v.y = softplus_f(acc[i][1] + bias.y);
        v.z = softplus_f(acc[i][2] + bias.z);
        v.w = softplus_f(acc[i][3] + bias.w);
        *reinterpret_cast<float4*>(&C[m * DI + col]) = v;
      }
    } else {
      const int col = tx * 4;    // 0..60 within BC tile
      if (col < 16) {
#pragma unroll
        for (int i = 0; i < 4; i++) {
          const size_t m = bm0 + ty * 4 + i;
          float4 v = {acc[i][0], acc[i][1], acc[i][2], acc[i][3]};
          *reinterpret_cast<float4*>(&Bb[m * DS + col]) = v;
        }
      } else if (col < 32) {
#pragma unroll
        for (int i = 0; i < 4; i++) {
          const size_t m = bm0 + ty * 4 + i;
          float4 v = {acc[i][0], acc[i][1], acc[i][2], acc[i][3]};
          *reinterpret_cast<float4*>(&Cb[m * DS + (col - 16)]) = v;
        }
      }
    }
  }
}

// ---------------- W_big precompute: [l][256 k][320] = [xw_dt @ dtw | xw_BC | 0pad] ----------------
__global__ __launch_bounds__(320) void build_wbig(
    const float* __restrict__ xw, const float* __restrict__ dtw,
    float* __restrict__ Wbig) {
  const int k = blockIdx.x;      // 0..255
  const int l = blockIdx.y;      // 0..1
  const int j = threadIdx.x;     // 0..319
  float v = 0.f;
  if (j < 256) {
#pragma unroll
    for (int r = 0; r < DR; r++)
      v += xw[(size_t)l * DI * 40 + k * 40 + r] * dtw[(size_t)l * DR * DI + r * DI + j];
  } else if (j < 288) {
    v = xw[(size_t)l * DI * 40 + k * 40 + 8 + (j - 256)];
  }
  Wbig[(size_t)l * DI * 320 + k * 320 + j] = v;
}

// ---------------- depthwise causal conv (4-tap) + bias + silu; also silu(res) in place ----------------
__global__ __launch_bounds__(256) void conv_silu_kernel(
    const float* __restrict__ xzr, float* __restrict__ xzw,
    const float* __restrict__ cw, const float* __restrict__ cb,
    float* __restrict__ u) {
  const int m = blockIdx.x;          // (bt*T + t)
  const int d = threadIdx.x;         // 0..255
  const int t = m & (T - 1);
  float acc = cb[d];
#pragma unroll
  for (int j = 0; j < 4; j++) {
    int tt = t - 3 + j;
    if (tt >= 0)
      acc += xzr[(size_t)(m - 3 + j) * 512 + d] * cw[d * 4 + j];
  }
  u[(size_t)m * DI + d] = fast_silu(acc);
  const size_t ra = (size_t)m * 512 + 256 + d;
  xzw[ra] = fast_silu(xzr[ra]);
}

// ---------------- chunked parallel scan (all 16 n-states per thread) ----------------
__global__ __launch_bounds__(256) void scan_phase1(
    const float* __restrict__ delta, const float* __restrict__ u,
    const float* __restrict__ Bb, const float* __restrict__ A_log,
    float* __restrict__ Pal, float* __restrict__ H) {
  const int c  = blockIdx.x;
  const int bt = blockIdx.y;
  const int d  = threadIdx.x;

  float An[16];
  const float4* al = reinterpret_cast<const float4*>(&A_log[d * DS]);
#pragma unroll
  for (int q = 0; q < 4; q++) {
    float4 a = al[q];
    An[q * 4 + 0] = -__expf(a.x);
    An[q * 4 + 1] = -__expf(a.y);
    An[q * 4 + 2] = -__expf(a.z);
    An[q * 4 + 3] = -__expf(a.w);
  }

  float h[16];
#pragma unroll
  for (int n = 0; n < 16; n++) h[n] = 0.f;
  float Sdl = 0.f;

  const size_t m0 = (size_t)bt * T + c * CL;
  for (int t = 0; t < CL; t++) {
    const size_t m = m0 + t;
    const float dl = delta[m * DI + d];
    const float uu = u[m * DI + d];
    const float du = dl * uu;
    Sdl += dl;
    const float4* bp = reinterpret_cast<const float4*>(&Bb[m * DS]);
    const float4 B0 = bp[0], B1 = bp[1], B2 = bp[2], B3 = bp[3];
    const float Bv[16] = {B0.x, B0.y, B0.z, B0.w, B1.x, B1.y, B1.z, B1.w,
                          B2.x, B2.y, B2.z, B2.w, B3.x, B3.y, B3.z, B3.w};
#pragma unroll
    for (int n = 0; n < 16; n++) {
      const float dA = __expf(dl * An[n]);
      h[n] = dA * h[n] + du * Bv[n];
    }
  }

  const size_t idx = ((size_t)c * BT + bt) * 4096 + (size_t)d * 16;
#pragma unroll
  for (int q = 0; q < 4; q++) {
    float4 hv = {h[q * 4 + 0], h[q * 4 + 1], h[q * 4 + 2], h[q * 4 + 3]};
    *reinterpret_cast<float4*>(&H[idx + q * 4]) = hv;
  }
#pragma unroll
  for (int q = 0; q < 4; q++) {
    float4 pv = {__expf(An[q * 4 + 0] * Sdl), __expf(An[q * 4 + 1] * Sdl),
                 __expf(An[q * 4 + 2] * Sdl), __expf(An[q * 4 + 3] * Sdl)};
    *reinterpret_cast<float4*>(&Pal[paddr(idx + q * 4)]) = pv;
  }
}

__global__ __launch_bounds__(256) void scan_phase2(
    const float* __restrict__ Pal, float* __restrict__ H) {
  const size_t i = (size_t)blockIdx.x * 256 + threadIdx.x;   // 0..SSZ-1
  float hin = 0.f;
#pragma unroll
  for (int c = 0; c < NC; c++) {
    const size_t idx = (size_t)c * SSZ + i;
    const float Pv = Pal[paddr(idx)];
    const float Hv = H[idx];
    H[idx] = hin;
    hin = Pv * hin + Hv;
  }
}

__global__ __launch_bounds__(256) void scan_phase3(
    const float* __restrict__ delta, const float* __restrict__ u,
    const float* __restrict__ Bb, const float* __restrict__ Cb,
    const float* __restrict__ xz,            // res half pre-silu'd by conv kernel
    const float* __restrict__ A_log, const float* __restrict__ Dp,
    const float* __restrict__ H, float* __restrict__ g) {
  const int c  = blockIdx.x;
  const int bt = blockIdx.y;
  const int d  = threadIdx.x;

  float An[16];
  const float4* al = reinterpret_cast<const float4*>(&A_log[d * DS]);
#pragma unroll
  for (int q = 0; q < 4; q++) {
    float4 a = al[q];
    An[q * 4 + 0] = -__expf(a.x);
    An[q * 4 + 1] = -__expf(a.y);
    An[q * 4 + 2] = -__expf(a.z);
    An[q * 4 + 3] = -__expf(a.w);
  }
  const float Dpd = Dp[d];

  float h[16];
  const size_t idx = ((size_t)c * BT + bt) * 4096 + (size_t)d * 16;
#pragma unroll
  for (int q = 0; q < 4; q++) {
    float4 hv = *reinterpret_cast<const float4*>(&H[idx + q * 4]);
    h[q * 4 + 0] = hv.x; h[q * 4 + 1] = hv.y; h[q * 4 + 2] = hv.z; h[q * 4 + 3] = hv.w;
  }

  const size_t m0 = (size_t)bt * T + c * CL;
  for (int t = 0; t < CL; t++) {
    const size_t m = m0 + t;
    const float dl = delta[m * DI + d];
    const float uu = u[m * DI + d];
    const float du = dl * uu;
    const float4* bp = reinterpret_cast<const float4*>(&Bb[m * DS]);
    const float4 B0 = bp[0], B1 = bp[1], B2 = bp[2], B3 = bp[3];
    const float4* cp = reinterpret_cast<const float4*>(&Cb[m * DS]);
    const float4 C0 = cp[0], C1 = cp[1], C2 = cp[2], C3 = cp[3];
    const float Bv[16] = {B0.x, B0.y, B0.z, B0.w, B1.x, B1.y, B1.z, B1.w,
                          B2.x, B2.y, B2.z, B2.w, B3.x, B3.y, B3.z, B3.w};
    const float Cv[16] = {C0.x, C0.y, C0.z, C0.w, C1.x, C1.y, C1.z, C1.w,
                          C2.x, C2.y, C2.z, C2.w, C3.x, C3.y, C3.z, C3.w};
    float y = 0.f;
#pragma unroll
    for (int n = 0; n < 16; n++) {
      const float dA = __expf(dl * An[n]);
      h[n] = dA * h[n] + du * Bv[n];
      y += h[n] * Cv[n];
    }
    const float rs = xz[m * 512 + 256 + d];       // already silu'd
    g[m * DI + d] = (y + uu * Dpd) * rs;          // aliases delta (same-thread RAW only)
  }
}

// ---------------- launch ----------------
extern "C" void kernel_launch(void* const* d_in, const int* in_sizes, int n_in,
                              void* d_out, int out_size, void* d_ws, size_t ws_size,
                              hipStream_t stream) {
  const float* x      = (const float*)d_in[0];
  const float* in_w   = (const float*)d_in[1];   // [2,128,512]
  const float* conv_w = (const float*)d_in[2];   // [2,256,1,4]
  const float* conv_b = (const float*)d_in[3];   // [2,256]
  const float* xw     = (const float*)d_in[4];   // [2,256,40]
  const float* dtw    = (const float*)d_in[5];   // [2,8,256]
  const float* dtb    = (const float*)d_in[6];   // [2,256]
  const float* A_log  = (const float*)d_in[7];   // [2,256,16]
  const float* Dp     = (const float*)d_in[8];   // [2,256]
  const float* ow     = (const float*)d_in[9];   // [2,256,128]
  float* out = (float*)d_out;
  float* ws  = (float*)d_ws;

  float* xz = ws;                          // 16384*512; u-pre half hosts P after conv
  float* u  = ws + 8388608;                // 16384*256
  float* dg = ws + 12582912;               // 16384*256 (delta, then g alias)
  float* Bb = ws + 16777216;               // 16384*16
  float* Cb = ws + 17039360;               // 16384*16
  float* hb = ws + 17301504;               // 16384*128
  float* Hb = ws + 19398656;               // NC*SSZ = 4194304 (end 23592960 floats = 94.4MB)
  // W_big scratch lives in d_out (only the final GEMM writes d_out, after last read of W_big)
  float* Wbig = out;                       // 2*256*320 = 163840 <= out_size (2097152)

  build_wbig<<<dim3(DI, 2), 320, 0, stream>>>(xw, dtw, Wbig);

  for (int l = 0; l < 2; l++) {
    const float* Ain = (l == 0) ? x : hb;
    float* dst = (l == 1) ? out : hb;

    gemm64<0><<<dim3(M_ROWS / 64, 512 / 64), 256, 0, stream>>>(
        Ain, in_w + (size_t)l * DM * 2 * DI, xz, nullptr, nullptr, nullptr,
        M_ROWS, 2 * DI, DM);

    conv_silu_kernel<<<M_ROWS, 256, 0, stream>>>(
        xz, xz, conv_w + (size_t)l * DI * 4, conv_b + (size_t)l * DI, u);

    gemm64<1><<<dim3(M_ROWS / 64, 320 / 64), 256, 0, stream>>>(
        u, Wbig + (size_t)l * DI * 320, dg, Bb, Cb, dtb + (size_t)l * DI,
        M_ROWS, 320, DI);

    scan_phase1<<<dim3(NC, BT), 256, 0, stream>>>(
        dg, u, Bb, A_log + (size_t)l * DI * DS, xz, Hb);

    scan_phase2<<<SSZ / 256, 256, 0, stream>>>(xz, Hb);

    scan_phase3<<<dim3(NC, BT), 256, 0, stream>>>(
        dg, u, Bb, Cb, xz, A_log + (size_t)l * DI * DS, Dp + (size_t)l * DI,
        Hb, dg);

    gemm64<0><<<dim3(M_ROWS / 64, DM / 64), 256, 0, stream>>>(
        dg, ow + (size_t)l * DI * DM, dst, nullptr, nullptr, nullptr,
        M_ROWS, DM, DI);
  }
}